// Round 2
// baseline (587.137 us; speedup 1.0000x reference)
//
#include <hip/hip_runtime.h>

#define BATCH 4
#define CIN   1024
#define CI    256
#define CO    1024
#define NSP   4096

typedef __attribute__((ext_vector_type(8))) short bf16x8;
typedef __attribute__((ext_vector_type(4))) float f32x4;

struct __align__(8) us4 { unsigned short x, y, z, w; };

#define DEVI __device__ __forceinline__

DEVI unsigned short f2bf(float f) {
  union { float f; unsigned u; } un; un.f = f;
  unsigned u = un.u;
  u += 0x7FFFu + ((u >> 16) & 1u);   // RNE
  return (unsigned short)(u >> 16);
}

DEVI void gl2lds16(const void* g, void* l) {
  __builtin_amdgcn_global_load_lds(
      (const __attribute__((address_space(1))) void*)g,
      (__attribute__((address_space(3))) void*)l, 16, 0, 0);
}

DEVI f32x4 mfma16(bf16x8 a, bf16x8 b, f32x4 c) {
  return __builtin_amdgcn_mfma_f32_16x16x32_bf16(a, b, c, 0, 0, 0);
}

// ---------------------------------------------------------------- prep small
__global__ __launch_bounds__(256) void k_prep(
    const float* __restrict__ w_key, const float* __restrict__ w_val,
    const float* __restrict__ w_out,
    const float* __restrict__ gamma, const float* __restrict__ beta,
    const float* __restrict__ mean,  const float* __restrict__ var,
    const float* __restrict__ b_key,
    unsigned short* __restrict__ wkv, unsigned short* __restrict__ wob,
    float* __restrict__ sq, float* __restrict__ bq)
{
  int idx = blockIdx.x * 256 + threadIdx.x;          // 0 .. 524287
  float wv = (idx < 262144) ? w_key[idx] : w_val[idx - 262144];
  wkv[idx] = f2bf(wv);
  if (idx < 262144) wob[idx] = f2bf(w_out[idx]);
  if (idx < 256) {
    float inv = gamma[idx] * rsqrtf(var[idx] + 1e-5f);
    sq[idx] = 0.25f * inv;                            // sqrt(1/16) folded into qk
    bq[idx] = 0.25f * (beta[idx] + (b_key[idx] - mean[idx]) * inv);
  }
}

// ------------------------------------------------------- x transpose -> bf16
__global__ __launch_bounds__(256) void k_xpose(const float* __restrict__ x,
                                               unsigned short* __restrict__ xT)
{
  __shared__ unsigned short tile[64][65];
  int b = blockIdx.z, k0 = blockIdx.y * 64, n0 = blockIdx.x * 64;
  int tid = threadIdx.x;
  int rr = tid >> 4, cc = tid & 15;
  const float* xb = x + ((size_t)b * CIN + k0) * NSP + n0;
#pragma unroll
  for (int p = 0; p < 4; ++p) {
    int row = p * 16 + rr;
    float4 v = *(const float4*)(xb + (size_t)row * NSP + cc * 4);
    tile[row][cc * 4 + 0] = f2bf(v.x);
    tile[row][cc * 4 + 1] = f2bf(v.y);
    tile[row][cc * 4 + 2] = f2bf(v.z);
    tile[row][cc * 4 + 3] = f2bf(v.w);
  }
  __syncthreads();
  unsigned short* xtb = xT + ((size_t)b * NSP + n0) * CIN + k0;
#pragma unroll
  for (int p = 0; p < 4; ++p) {
    int n = p * 16 + rr;
    int kq = cc * 4;
    us4 pk;
    pk.x = tile[kq + 0][n]; pk.y = tile[kq + 1][n];
    pk.z = tile[kq + 2][n]; pk.w = tile[kq + 3][n];
    *(us4*)(xtb + (size_t)n * CIN + kq) = pk;
  }
}

// -------------------------------------------- 128x128 NT GEMM core (bf16)
template<int KDIM>
DEVI void gemm_core(const unsigned short* __restrict__ Ab,
                    const unsigned short* __restrict__ Bb,
                    unsigned short* ldsA, unsigned short* ldsB,
                    f32x4 acc[4][4], int tid)
{
  const int lane = tid & 63, wave = tid >> 6;
  const int q = lane >> 4, ln = lane & 15;
  const int wm = wave & 1, wn = wave >> 1;

  int aoff[4][2], boff[4][2];
#pragma unroll
  for (int f = 0; f < 4; ++f) {
    int ra = wm * 64 + f * 16 + ln;
    aoff[f][0] = (ra * 8 + ((q)     ^ (ra & 7))) * 8;
    aoff[f][1] = (ra * 8 + ((q + 4) ^ (ra & 7))) * 8;
    int rb = wn * 64 + f * 16 + ln;
    boff[f][0] = (rb * 8 + ((q)     ^ (rb & 7))) * 8;
    boff[f][1] = (rb * 8 + ((q + 4) ^ (rb & 7))) * 8;
  }
  int sgo[4];
#pragma unroll
  for (int i = 0; i < 4; ++i) {
    int s = i * 256 + tid;
    int row = s >> 3;
    int c8 = (s & 7) ^ (row & 7);
    sgo[i] = row * KDIM + c8 * 8;
  }
  for (int k0 = 0; k0 < KDIM; k0 += 64) {
#pragma unroll
    for (int i = 0; i < 4; ++i) {
      gl2lds16(Ab + sgo[i] + k0, ldsA + (i * 256 + wave * 64) * 8);
      gl2lds16(Bb + sgo[i] + k0, ldsB + (i * 256 + wave * 64) * 8);
    }
    __syncthreads();
#pragma unroll
    for (int kk = 0; kk < 2; ++kk) {
      bf16x8 af[4], bfr[4];
#pragma unroll
      for (int f = 0; f < 4; ++f) af[f]  = *(const bf16x8*)(ldsA + aoff[f][kk]);
#pragma unroll
      for (int f = 0; f < 4; ++f) bfr[f] = *(const bf16x8*)(ldsB + boff[f][kk]);
#pragma unroll
      for (int mf = 0; mf < 4; ++mf)
#pragma unroll
        for (int nf = 0; nf < 4; ++nf)
          acc[mf][nf] = mfma16(af[mf], bfr[nf], acc[mf][nf]);
    }
    __syncthreads();
  }
}

// ------------------------------------------------- qk/value conv (fused)
__global__ __launch_bounds__(256) void k_convqkv(
    const unsigned short* __restrict__ wkv,   // [512][1024]
    const unsigned short* __restrict__ xT,    // [B][4096][1024]
    const float* __restrict__ sq, const float* __restrict__ bq,
    const float* __restrict__ bval,
    unsigned short* __restrict__ qkT,         // [B][4096][256]
    unsigned short* __restrict__ vv)          // [B][256][4096]
{
  __shared__ __align__(16) unsigned short ldsA[128 * 64];
  __shared__ __align__(16) unsigned short ldsB[128 * 64];
  int b = blockIdx.z, m0 = blockIdx.y * 128, n0 = blockIdx.x * 128;
  int tid = threadIdx.x;
  f32x4 z = {0.f, 0.f, 0.f, 0.f};
  f32x4 acc[4][4];
#pragma unroll
  for (int i = 0; i < 4; ++i)
#pragma unroll
    for (int j = 0; j < 4; ++j) acc[i][j] = z;

  gemm_core<CIN>(wkv + (size_t)m0 * CIN, xT + ((size_t)b * NSP + n0) * CIN,
                 ldsA, ldsB, acc, tid);

  int lane = tid & 63, wave = tid >> 6, q = lane >> 4, ln = lane & 15;
  int wm = wave & 1, wn = wave >> 1;
  if (m0 < 256) {
#pragma unroll
    for (int mf = 0; mf < 4; ++mf) {
      int cb = m0 + wm * 64 + mf * 16 + q * 4;
      float s0_ = sq[cb + 0], s1_ = sq[cb + 1], s2_ = sq[cb + 2], s3_ = sq[cb + 3];
      float b0_ = bq[cb + 0], b1_ = bq[cb + 1], b2_ = bq[cb + 2], b3_ = bq[cb + 3];
#pragma unroll
      for (int nf = 0; nf < 4; ++nf) {
        int n = n0 + wn * 64 + nf * 16 + ln;
        us4 pk;
        pk.x = f2bf(acc[mf][nf][0] * s0_ + b0_);
        pk.y = f2bf(acc[mf][nf][1] * s1_ + b1_);
        pk.z = f2bf(acc[mf][nf][2] * s2_ + b2_);
        pk.w = f2bf(acc[mf][nf][3] * s3_ + b3_);
        *(us4*)(qkT + ((size_t)b * NSP + n) * CI + cb) = pk;
      }
    }
  } else {
#pragma unroll
    for (int mf = 0; mf < 4; ++mf) {
      int cb = (m0 - 256) + wm * 64 + mf * 16 + q * 4;
#pragma unroll
      for (int r = 0; r < 4; ++r) {
        float bv = bval[cb + r];
#pragma unroll
        for (int nf = 0; nf < 4; ++nf) {
          int n = n0 + wn * 64 + nf * 16 + ln;
          vv[((size_t)b * CI + (cb + r)) * NSP + n] = f2bf(acc[mf][nf][r] + bv);
        }
      }
    }
  }
}

// ------------------------------------------------------ fused attention
// 1024 threads = 16 waves = 4 wave-sets; set s handles j in [s*1024, s*1024+1024)
// for all 64 Q rows. Per-set private K/V LDS tiles; online-softmax partials
// merged through LDS at the end.
__global__ __launch_bounds__(1024) void k_attn(
    const unsigned short* __restrict__ qkT,   // [B][4096][256]
    const unsigned short* __restrict__ vv,    // [B][256][4096]
    unsigned short* __restrict__ ctx)         // [B][4096][256]
{
  // 4 x (Kt 32x256 + Vt 256x32) = 128 KiB; Obuf (64x260 f32 = 65 KiB) overlays it
  __shared__ __align__(16) unsigned short TileMem[4 * (32 * 256 + 256 * 32)];
  __shared__ __align__(16) unsigned short Pl[16 * 512];   // per-wave P staging
  __shared__ float Msm[4][64];
  __shared__ float Lsm[4][64];
  __shared__ float Ism[64];

  int bid = blockIdx.x;                       // 256 blocks
  int b  = (bid & 7) >> 1;
  int qt = ((bid >> 3) << 1) | (bid & 1);
  int n0 = qt * 64;
  int tid = threadIdx.x, lane = tid & 63, wave = tid >> 6;
  int wset = wave >> 2;                       // j-split index 0..3
  int wq   = wave & 3;                        // Q-row group within set
  int stid = tid & 255;                       // thread id within set
  int q = lane >> 4, ln = lane & 15;
  const unsigned short* qkb = qkT + (size_t)b * NSP * CI;
  const unsigned short* vb  = vv  + (size_t)b * CI * NSP;

  unsigned short* Kt = TileMem + wset * (32 * 256 + 256 * 32);
  unsigned short* Vt = Kt + 32 * 256;

  // Q fragments in registers: wave's 16 q-rows, all 256 channels
  bf16x8 Qf[8];
  {
    const unsigned short* qrow = qkb + (size_t)(n0 + wq * 16 + ln) * CI + q * 8;
#pragma unroll
    for (int t = 0; t < 8; ++t) Qf[t] = *(const bf16x8*)(qrow + t * 32);
  }

  int koff[2][8];
#pragma unroll
  for (int js = 0; js < 2; ++js) {
    int j = js * 16 + ln;
#pragma unroll
    for (int t = 0; t < 8; ++t) {
      int cc = t * 4 + q;
      koff[js][t] = (j * 32 + ((cc & 24) | ((cc ^ j) & 7))) * 8;
    }
  }
  int voff[16];
#pragma unroll
  for (int cf = 0; cf < 16; ++cf) {
    int c = cf * 16 + ln;
    voff[cf] = (c * 4 + ((q ^ (c >> 1)) & 3)) * 8;
  }
  int proff = wave * 512 + (ln * 4 + ((q ^ (ln >> 1)) & 3)) * 8;
  int pw[2][4];
#pragma unroll
  for (int js = 0; js < 2; ++js)
#pragma unroll
    for (int r = 0; r < 4; ++r) {
      int m = q * 4 + r;
      int j = js * 16 + ln;
      int cc = j >> 3;
      pw[js][r] = wave * 512 + (m * 4 + ((cc ^ (m >> 1)) & 3)) * 8 + (j & 7);
    }

  int gko[4], gvo[4];
#pragma unroll
  for (int i = 0; i < 4; ++i) {
    int s = i * 256 + stid;
    int j = s >> 5, f = s & 31;
    gko[i] = j * CI + ((f & 24) | ((f ^ j) & 7)) * 8;
    int c = s >> 2;
    gvo[i] = c * NSP + ((s ^ (c >> 1)) & 3) * 8;
  }

  f32x4 O[16];
  f32x4 z = {0.f, 0.f, 0.f, 0.f};
#pragma unroll
  for (int cf = 0; cf < 16; ++cf) O[cf] = z;
  float mrow[4] = {-1e30f, -1e30f, -1e30f, -1e30f};
  float lrow[4] = {0.f, 0.f, 0.f, 0.f};

  int jbase = wset * 1024;
  for (int it = 0; it < 32; ++it) {
    int j0 = jbase + it * 32;
#pragma unroll
    for (int i = 0; i < 4; ++i)
      gl2lds16(qkb + (size_t)j0 * CI + gko[i], Kt + (i * 256 + wq * 64) * 8);
#pragma unroll
    for (int i = 0; i < 4; ++i)
      gl2lds16(vb + j0 + gvo[i], Vt + (i * 256 + wq * 64) * 8);
    __syncthreads();

    f32x4 s0 = z, s1 = z;
#pragma unroll
    for (int t = 0; t < 8; ++t) {
      bf16x8 kf0 = *(const bf16x8*)(Kt + koff[0][t]);
      bf16x8 kf1 = *(const bf16x8*)(Kt + koff[1][t]);
      s0 = mfma16(Qf[t], kf0, s0);
      s1 = mfma16(Qf[t], kf1, s1);
    }

    float alr[4];
#pragma unroll
    for (int r = 0; r < 4; ++r) {
      float v0 = s0[r], v1 = s1[r];
      float mx = fmaxf(v0, v1);
      mx = fmaxf(mx, __shfl_xor(mx, 1));
      mx = fmaxf(mx, __shfl_xor(mx, 2));
      mx = fmaxf(mx, __shfl_xor(mx, 4));
      mx = fmaxf(mx, __shfl_xor(mx, 8));
      float mnew = fmaxf(mrow[r], mx);
      float p0 = __expf(v0 - mnew);
      float p1 = __expf(v1 - mnew);
      float al = __expf(mrow[r] - mnew);
      float sm = p0 + p1;
      sm += __shfl_xor(sm, 1);
      sm += __shfl_xor(sm, 2);
      sm += __shfl_xor(sm, 4);
      sm += __shfl_xor(sm, 8);
      lrow[r] = lrow[r] * al + sm;
      mrow[r] = mnew;
      alr[r] = al;
      Pl[pw[0][r]] = f2bf(p0);
      Pl[pw[1][r]] = f2bf(p1);
    }
    f32x4 alv = {alr[0], alr[1], alr[2], alr[3]};
#pragma unroll
    for (int cf = 0; cf < 16; ++cf) O[cf] *= alv;

    bf16x8 pf = *(const bf16x8*)(Pl + proff);
#pragma unroll
    for (int cf = 0; cf < 16; ++cf) {
      bf16x8 vf = *(const bf16x8*)(Vt + voff[cf]);
      O[cf] = mfma16(pf, vf, O[cf]);
    }
    __syncthreads();
  }

  // ---- merge 4 per-set online-softmax partials ----
  if (ln == 0) {
#pragma unroll
    for (int r = 0; r < 4; ++r) {
      int row = wq * 16 + q * 4 + r;
      Msm[wset][row] = mrow[r];
      Lsm[wset][row] = lrow[r];
    }
  }
  __syncthreads();

  float alr[4];
#pragma unroll
  for (int r = 0; r < 4; ++r) {
    int row = wq * 16 + q * 4 + r;
    float m0_ = Msm[0][row], m1_ = Msm[1][row], m2_ = Msm[2][row], m3_ = Msm[3][row];
    float mf_ = fmaxf(fmaxf(m0_, m1_), fmaxf(m2_, m3_));
    alr[r] = __expf(mrow[r] - mf_);
    if (wset == 0 && ln == 0) {
      float lf = __expf(m0_ - mf_) * Lsm[0][row] + __expf(m1_ - mf_) * Lsm[1][row]
               + __expf(m2_ - mf_) * Lsm[2][row] + __expf(m3_ - mf_) * Lsm[3][row];
      Ism[row] = 1.0f / lf;
    }
  }
  f32x4 alv = {alr[0], alr[1], alr[2], alr[3]};
#pragma unroll
  for (int cf = 0; cf < 16; ++cf) O[cf] *= alv;

  float* Obuf = (float*)TileMem;              // [64][260] fp32, overlays tiles
  __syncthreads();                            // all sets done reading Kt/Vt
  if (wset == 0) {
#pragma unroll
    for (int cf = 0; cf < 16; ++cf)
#pragma unroll
      for (int r = 0; r < 4; ++r)
        Obuf[(wq * 16 + q * 4 + r) * 260 + cf * 16 + ln] = O[cf][r];
  }
  __syncthreads();
  if (wset == 1) {
#pragma unroll
    for (int cf = 0; cf < 16; ++cf)
#pragma unroll
      for (int r = 0; r < 4; ++r)
        Obuf[(wq * 16 + q * 4 + r) * 260 + cf * 16 + ln] += O[cf][r];
  }
  __syncthreads();
  if (wset == 2) {
#pragma unroll
    for (int cf = 0; cf < 16; ++cf)
#pragma unroll
      for (int r = 0; r < 4; ++r)
        Obuf[(wq * 16 + q * 4 + r) * 260 + cf * 16 + ln] += O[cf][r];
  }
  __syncthreads();
  if (wset == 3) {
#pragma unroll
    for (int cf = 0; cf < 16; ++cf)
#pragma unroll
      for (int r = 0; r < 4; ++r)
        Obuf[(wq * 16 + q * 4 + r) * 260 + cf * 16 + ln] += O[cf][r];
  }
  __syncthreads();

  // final normalize + store: wave handles rows [wave*4, wave*4+4)
#pragma unroll
  for (int rr = 0; rr < 4; ++rr) {
    int row = wave * 4 + rr;
    float inv = Ism[row];
    f32x4 v = *(const f32x4*)(Obuf + row * 260 + lane * 4);
    us4 pk;
    pk.x = f2bf(v[0] * inv);
    pk.y = f2bf(v[1] * inv);
    pk.z = f2bf(v[2] * inv);
    pk.w = f2bf(v[3] * inv);
    *(us4*)(ctx + ((size_t)b * NSP + n0 + row) * CI + lane * 4) = pk;
  }
}

// ------------------------------------------------------ output conv
__global__ __launch_bounds__(256) void k_convout(
    const unsigned short* __restrict__ wo,    // [1024][256]
    const unsigned short* __restrict__ ctx,   // [B][4096][256]
    const float* __restrict__ bout,
    float* __restrict__ out)                  // [B][1024][4096]
{
  __shared__ __align__(16) unsigned short ldsA[128 * 64];
  __shared__ __align__(16) unsigned short ldsB[128 * 64];
  int b = blockIdx.z, m0 = blockIdx.y * 128, n0 = blockIdx.x * 128;
  int tid = threadIdx.x;
  f32x4 z = {0.f, 0.f, 0.f, 0.f};
  f32x4 acc[4][4];
#pragma unroll
  for (int i = 0; i < 4; ++i)
#pragma unroll
    for (int j = 0; j < 4; ++j) acc[i][j] = z;

  gemm_core<CI>(wo + (size_t)m0 * CI, ctx + ((size_t)b * NSP + n0) * CI,
                ldsA, ldsB, acc, tid);

  int lane = tid & 63, wave = tid >> 6, q = lane >> 4, ln = lane & 15;
  int wm = wave & 1, wn = wave >> 1;
#pragma unroll
  for (int mf = 0; mf < 4; ++mf) {
    int cb = m0 + wm * 64 + mf * 16 + q * 4;
    float bo0 = bout[cb + 0], bo1 = bout[cb + 1], bo2 = bout[cb + 2], bo3 = bout[cb + 3];
#pragma unroll
    for (int nf = 0; nf < 4; ++nf) {
      int n = n0 + wn * 64 + nf * 16 + ln;
      float* p = out + ((size_t)b * CO + cb) * NSP + n;
      p[0 * (size_t)NSP] = acc[mf][nf][0] + bo0;
      p[1 * (size_t)NSP] = acc[mf][nf][1] + bo1;
      p[2 * (size_t)NSP] = acc[mf][nf][2] + bo2;
      p[3 * (size_t)NSP] = acc[mf][nf][3] + bo3;
    }
  }
}

// ---------------------------------------------------------------- launch
extern "C" void kernel_launch(void* const* d_in, const int* in_sizes, int n_in,
                              void* d_out, int out_size, void* d_ws, size_t ws_size,
                              hipStream_t stream) {
  const float* x     = (const float*)d_in[0];
  const float* w_key = (const float*)d_in[1];
  const float* b_key = (const float*)d_in[2];
  const float* gamma = (const float*)d_in[3];
  const float* beta  = (const float*)d_in[4];
  const float* mean  = (const float*)d_in[5];
  const float* var   = (const float*)d_in[6];
  const float* w_val = (const float*)d_in[7];
  const float* b_val = (const float*)d_in[8];
  const float* w_out = (const float*)d_in[9];
  const float* b_out = (const float*)d_in[10];
  float* out = (float*)d_out;

  char* ws = (char*)d_ws;
  unsigned short* xT  = (unsigned short*)(ws);               // 32 MiB
  unsigned short* wkv = (unsigned short*)(ws + 33554432);    // 1 MiB
  unsigned short* wob = (unsigned short*)(ws + 34603008);    // 512 KiB
  unsigned short* qkT = (unsigned short*)(ws + 35127296);    // 8 MiB
  unsigned short* vv  = (unsigned short*)(ws + 43515904);    // 8 MiB
  unsigned short* ctx = (unsigned short*)(ws + 51904512);    // 8 MiB
  float* sq = (float*)(ws + 60293120);                       // 1 KiB
  float* bq = (float*)(ws + 60294144);                       // 1 KiB

  k_prep<<<2048, 256, 0, stream>>>(w_key, w_val, w_out, gamma, beta, mean, var,
                                   b_key, wkv, wob, sq, bq);
  k_xpose<<<dim3(64, 16, 4), 256, 0, stream>>>(x, xT);
  k_convqkv<<<dim3(32, 4, 4), 256, 0, stream>>>(wkv, xT, sq, bq, b_val, qkT, vv);
  k_attn<<<256, 1024, 0, stream>>>(qkT, vv, ctx);
  k_convout<<<dim3(32, 8, 4), 256, 0, stream>>>(wob, ctx, b_out, out);
}

// Round 3
// 581.319 us; speedup vs baseline: 1.0100x; 1.0100x over previous
//
#include <hip/hip_runtime.h>

#define BATCH 4
#define CIN   1024
#define CI    256
#define CO    1024
#define NSP   4096

typedef __attribute__((ext_vector_type(8))) short bf16x8;
typedef __attribute__((ext_vector_type(4))) float f32x4;

struct __align__(8) us4 { unsigned short x, y, z, w; };

#define DEVI __device__ __forceinline__

DEVI unsigned short f2bf(float f) {
  union { float f; unsigned u; } un; un.f = f;
  unsigned u = un.u;
  u += 0x7FFFu + ((u >> 16) & 1u);   // RNE
  return (unsigned short)(u >> 16);
}

DEVI void gl2lds16(const void* g, void* l) {
  __builtin_amdgcn_global_load_lds(
      (const __attribute__((address_space(1))) void*)g,
      (__attribute__((address_space(3))) void*)l, 16, 0, 0);
}

DEVI f32x4 mfma16(bf16x8 a, bf16x8 b, f32x4 c) {
  return __builtin_amdgcn_mfma_f32_16x16x32_bf16(a, b, c, 0, 0, 0);
}

// ---------------------------------------------------------------- prep small
__global__ __launch_bounds__(256) void k_prep(
    const float* __restrict__ w_key, const float* __restrict__ w_val,
    const float* __restrict__ w_out,
    const float* __restrict__ gamma, const float* __restrict__ beta,
    const float* __restrict__ mean,  const float* __restrict__ var,
    const float* __restrict__ b_key,
    unsigned short* __restrict__ wkv, unsigned short* __restrict__ wob,
    float* __restrict__ sq, float* __restrict__ bq)
{
  int idx = blockIdx.x * 256 + threadIdx.x;          // 0 .. 524287
  float wv = (idx < 262144) ? w_key[idx] : w_val[idx - 262144];
  wkv[idx] = f2bf(wv);
  if (idx < 262144) wob[idx] = f2bf(w_out[idx]);
  if (idx < 256) {
    float inv = gamma[idx] * rsqrtf(var[idx] + 1e-5f);
    sq[idx] = 0.25f * inv;                            // sqrt(1/16) folded into qk
    bq[idx] = 0.25f * (beta[idx] + (b_key[idx] - mean[idx]) * inv);
  }
}

// ------------------------------------------------------- x transpose -> bf16
__global__ __launch_bounds__(256) void k_xpose(const float* __restrict__ x,
                                               unsigned short* __restrict__ xT)
{
  __shared__ unsigned short tile[64][65];
  int b = blockIdx.z, k0 = blockIdx.y * 64, n0 = blockIdx.x * 64;
  int tid = threadIdx.x;
  int rr = tid >> 4, cc = tid & 15;
  const float* xb = x + ((size_t)b * CIN + k0) * NSP + n0;
#pragma unroll
  for (int p = 0; p < 4; ++p) {
    int row = p * 16 + rr;
    float4 v = *(const float4*)(xb + (size_t)row * NSP + cc * 4);
    tile[row][cc * 4 + 0] = f2bf(v.x);
    tile[row][cc * 4 + 1] = f2bf(v.y);
    tile[row][cc * 4 + 2] = f2bf(v.z);
    tile[row][cc * 4 + 3] = f2bf(v.w);
  }
  __syncthreads();
  unsigned short* xtb = xT + ((size_t)b * NSP + n0) * CIN + k0;
#pragma unroll
  for (int p = 0; p < 4; ++p) {
    int n = p * 16 + rr;
    int kq = cc * 4;
    us4 pk;
    pk.x = tile[kq + 0][n]; pk.y = tile[kq + 1][n];
    pk.z = tile[kq + 2][n]; pk.w = tile[kq + 3][n];
    *(us4*)(xtb + (size_t)n * CIN + kq) = pk;
  }
}

// -------------------------------------------- 128x128 NT GEMM core (bf16)
template<int KDIM>
DEVI void gemm_core(const unsigned short* __restrict__ Ab,
                    const unsigned short* __restrict__ Bb,
                    unsigned short* ldsA, unsigned short* ldsB,
                    f32x4 acc[4][4], int tid)
{
  const int lane = tid & 63, wave = tid >> 6;
  const int q = lane >> 4, ln = lane & 15;
  const int wm = wave & 1, wn = wave >> 1;

  int aoff[4][2], boff[4][2];
#pragma unroll
  for (int f = 0; f < 4; ++f) {
    int ra = wm * 64 + f * 16 + ln;
    aoff[f][0] = (ra * 8 + ((q)     ^ (ra & 7))) * 8;
    aoff[f][1] = (ra * 8 + ((q + 4) ^ (ra & 7))) * 8;
    int rb = wn * 64 + f * 16 + ln;
    boff[f][0] = (rb * 8 + ((q)     ^ (rb & 7))) * 8;
    boff[f][1] = (rb * 8 + ((q + 4) ^ (rb & 7))) * 8;
  }
  int sgo[4];
#pragma unroll
  for (int i = 0; i < 4; ++i) {
    int s = i * 256 + tid;
    int row = s >> 3;
    int c8 = (s & 7) ^ (row & 7);
    sgo[i] = row * KDIM + c8 * 8;
  }
  for (int k0 = 0; k0 < KDIM; k0 += 64) {
#pragma unroll
    for (int i = 0; i < 4; ++i) {
      gl2lds16(Ab + sgo[i] + k0, ldsA + (i * 256 + wave * 64) * 8);
      gl2lds16(Bb + sgo[i] + k0, ldsB + (i * 256 + wave * 64) * 8);
    }
    __syncthreads();
#pragma unroll
    for (int kk = 0; kk < 2; ++kk) {
      bf16x8 af[4], bfr[4];
#pragma unroll
      for (int f = 0; f < 4; ++f) af[f]  = *(const bf16x8*)(ldsA + aoff[f][kk]);
#pragma unroll
      for (int f = 0; f < 4; ++f) bfr[f] = *(const bf16x8*)(ldsB + boff[f][kk]);
#pragma unroll
      for (int mf = 0; mf < 4; ++mf)
#pragma unroll
        for (int nf = 0; nf < 4; ++nf)
          acc[mf][nf] = mfma16(af[mf], bfr[nf], acc[mf][nf]);
    }
    __syncthreads();
  }
}

// ------------------------------------------------- qk/value conv (fused)
__global__ __launch_bounds__(256) void k_convqkv(
    const unsigned short* __restrict__ wkv,   // [512][1024]
    const unsigned short* __restrict__ xT,    // [B][4096][1024]
    const float* __restrict__ sq, const float* __restrict__ bq,
    const float* __restrict__ bval,
    unsigned short* __restrict__ qkT,         // [B][4096][256]
    unsigned short* __restrict__ vv)          // [B][256][4096]
{
  __shared__ __align__(16) unsigned short ldsA[128 * 64];
  __shared__ __align__(16) unsigned short ldsB[128 * 64];
  int b = blockIdx.z, m0 = blockIdx.y * 128, n0 = blockIdx.x * 128;
  int tid = threadIdx.x;
  f32x4 z = {0.f, 0.f, 0.f, 0.f};
  f32x4 acc[4][4];
#pragma unroll
  for (int i = 0; i < 4; ++i)
#pragma unroll
    for (int j = 0; j < 4; ++j) acc[i][j] = z;

  gemm_core<CIN>(wkv + (size_t)m0 * CIN, xT + ((size_t)b * NSP + n0) * CIN,
                 ldsA, ldsB, acc, tid);

  int lane = tid & 63, wave = tid >> 6, q = lane >> 4, ln = lane & 15;
  int wm = wave & 1, wn = wave >> 1;
  if (m0 < 256) {
#pragma unroll
    for (int mf = 0; mf < 4; ++mf) {
      int cb = m0 + wm * 64 + mf * 16 + q * 4;
      float s0_ = sq[cb + 0], s1_ = sq[cb + 1], s2_ = sq[cb + 2], s3_ = sq[cb + 3];
      float b0_ = bq[cb + 0], b1_ = bq[cb + 1], b2_ = bq[cb + 2], b3_ = bq[cb + 3];
#pragma unroll
      for (int nf = 0; nf < 4; ++nf) {
        int n = n0 + wn * 64 + nf * 16 + ln;
        us4 pk;
        pk.x = f2bf(acc[mf][nf][0] * s0_ + b0_);
        pk.y = f2bf(acc[mf][nf][1] * s1_ + b1_);
        pk.z = f2bf(acc[mf][nf][2] * s2_ + b2_);
        pk.w = f2bf(acc[mf][nf][3] * s3_ + b3_);
        *(us4*)(qkT + ((size_t)b * NSP + n) * CI + cb) = pk;
      }
    }
  } else {
#pragma unroll
    for (int mf = 0; mf < 4; ++mf) {
      int cb = (m0 - 256) + wm * 64 + mf * 16 + q * 4;
#pragma unroll
      for (int r = 0; r < 4; ++r) {
        float bv = bval[cb + r];
#pragma unroll
        for (int nf = 0; nf < 4; ++nf) {
          int n = n0 + wn * 64 + nf * 16 + ln;
          vv[((size_t)b * CI + (cb + r)) * NSP + n] = f2bf(acc[mf][nf][r] + bv);
        }
      }
    }
  }
}

// ------------------------------------------------------ fused attention
// 1024 threads = 16 waves = 4 wave-sets; set s handles j in [s*1024, s*1024+1024)
// for all 64 Q rows. Per-set private K/V LDS tiles; online-softmax partials
// merged through LDS at the end.
// __launch_bounds__(1024, 4): min 4 waves/EU = exactly 1 block/CU -> VGPR cap
// 128 (no spill; R1's default cap of 64 VGPR spilled O[] to scratch: 750 MB
// FETCH, 410 us).
__global__ __launch_bounds__(1024, 4) void k_attn(
    const unsigned short* __restrict__ qkT,   // [B][4096][256]
    const unsigned short* __restrict__ vv,    // [B][256][4096]
    unsigned short* __restrict__ ctx)         // [B][4096][256]
{
  // 4 x (Kt 32x256 + Vt 256x32) = 128 KiB; Obuf (64x260 f32 = 65 KiB) overlays it
  __shared__ __align__(16) unsigned short TileMem[4 * (32 * 256 + 256 * 32)];
  __shared__ __align__(16) unsigned short Pl[16 * 512];   // per-wave P staging
  __shared__ float Msm[4][64];
  __shared__ float Lsm[4][64];
  __shared__ float Ism[64];

  int bid = blockIdx.x;                       // 256 blocks
  int b  = (bid & 7) >> 1;
  int qt = ((bid >> 3) << 1) | (bid & 1);
  int n0 = qt * 64;
  int tid = threadIdx.x, lane = tid & 63, wave = tid >> 6;
  int wset = wave >> 2;                       // j-split index 0..3
  int wq   = wave & 3;                        // Q-row group within set
  int stid = tid & 255;                       // thread id within set
  int q = lane >> 4, ln = lane & 15;
  const unsigned short* qkb = qkT + (size_t)b * NSP * CI;
  const unsigned short* vb  = vv  + (size_t)b * CI * NSP;

  unsigned short* Kt = TileMem + wset * (32 * 256 + 256 * 32);
  unsigned short* Vt = Kt + 32 * 256;

  // Q fragments in registers: wave's 16 q-rows, all 256 channels
  bf16x8 Qf[8];
  {
    const unsigned short* qrow = qkb + (size_t)(n0 + wq * 16 + ln) * CI + q * 8;
#pragma unroll
    for (int t = 0; t < 8; ++t) Qf[t] = *(const bf16x8*)(qrow + t * 32);
  }

  int koff[2][8];
#pragma unroll
  for (int js = 0; js < 2; ++js) {
    int j = js * 16 + ln;
#pragma unroll
    for (int t = 0; t < 8; ++t) {
      int cc = t * 4 + q;
      koff[js][t] = (j * 32 + ((cc & 24) | ((cc ^ j) & 7))) * 8;
    }
  }
  int voff[16];
#pragma unroll
  for (int cf = 0; cf < 16; ++cf) {
    int c = cf * 16 + ln;
    voff[cf] = (c * 4 + ((q ^ (c >> 1)) & 3)) * 8;
  }
  int proff = wave * 512 + (ln * 4 + ((q ^ (ln >> 1)) & 3)) * 8;
  int pw[2][4];
#pragma unroll
  for (int js = 0; js < 2; ++js)
#pragma unroll
    for (int r = 0; r < 4; ++r) {
      int m = q * 4 + r;
      int j = js * 16 + ln;
      int cc = j >> 3;
      pw[js][r] = wave * 512 + (m * 4 + ((cc ^ (m >> 1)) & 3)) * 8 + (j & 7);
    }

  int gko[4], gvo[4];
#pragma unroll
  for (int i = 0; i < 4; ++i) {
    int s = i * 256 + stid;
    int j = s >> 5, f = s & 31;
    gko[i] = j * CI + ((f & 24) | ((f ^ j) & 7)) * 8;
    int c = s >> 2;
    gvo[i] = c * NSP + ((s ^ (c >> 1)) & 3) * 8;
  }

  f32x4 O[16];
  f32x4 z = {0.f, 0.f, 0.f, 0.f};
#pragma unroll
  for (int cf = 0; cf < 16; ++cf) O[cf] = z;
  float mrow[4] = {-1e30f, -1e30f, -1e30f, -1e30f};
  float lrow[4] = {0.f, 0.f, 0.f, 0.f};

  int jbase = wset * 1024;
  for (int it = 0; it < 32; ++it) {
    int j0 = jbase + it * 32;
#pragma unroll
    for (int i = 0; i < 4; ++i)
      gl2lds16(qkb + (size_t)j0 * CI + gko[i], Kt + (i * 256 + wq * 64) * 8);
#pragma unroll
    for (int i = 0; i < 4; ++i)
      gl2lds16(vb + j0 + gvo[i], Vt + (i * 256 + wq * 64) * 8);
    __syncthreads();

    f32x4 s0 = z, s1 = z;
#pragma unroll
    for (int t = 0; t < 8; ++t) {
      bf16x8 kf0 = *(const bf16x8*)(Kt + koff[0][t]);
      bf16x8 kf1 = *(const bf16x8*)(Kt + koff[1][t]);
      s0 = mfma16(Qf[t], kf0, s0);
      s1 = mfma16(Qf[t], kf1, s1);
    }

    float alr[4];
#pragma unroll
    for (int r = 0; r < 4; ++r) {
      float v0 = s0[r], v1 = s1[r];
      float mx = fmaxf(v0, v1);
      mx = fmaxf(mx, __shfl_xor(mx, 1));
      mx = fmaxf(mx, __shfl_xor(mx, 2));
      mx = fmaxf(mx, __shfl_xor(mx, 4));
      mx = fmaxf(mx, __shfl_xor(mx, 8));
      float mnew = fmaxf(mrow[r], mx);
      float p0 = __expf(v0 - mnew);
      float p1 = __expf(v1 - mnew);
      float al = __expf(mrow[r] - mnew);
      float sm = p0 + p1;
      sm += __shfl_xor(sm, 1);
      sm += __shfl_xor(sm, 2);
      sm += __shfl_xor(sm, 4);
      sm += __shfl_xor(sm, 8);
      lrow[r] = lrow[r] * al + sm;
      mrow[r] = mnew;
      alr[r] = al;
      Pl[pw[0][r]] = f2bf(p0);
      Pl[pw[1][r]] = f2bf(p1);
    }
    f32x4 alv = {alr[0], alr[1], alr[2], alr[3]};
#pragma unroll
    for (int cf = 0; cf < 16; ++cf) O[cf] *= alv;

    bf16x8 pf = *(const bf16x8*)(Pl + proff);
#pragma unroll
    for (int cf = 0; cf < 16; ++cf) {
      bf16x8 vf = *(const bf16x8*)(Vt + voff[cf]);
      O[cf] = mfma16(pf, vf, O[cf]);
    }
    __syncthreads();
  }

  // ---- merge 4 per-set online-softmax partials ----
  if (ln == 0) {
#pragma unroll
    for (int r = 0; r < 4; ++r) {
      int row = wq * 16 + q * 4 + r;
      Msm[wset][row] = mrow[r];
      Lsm[wset][row] = lrow[r];
    }
  }
  __syncthreads();

  float alr[4];
#pragma unroll
  for (int r = 0; r < 4; ++r) {
    int row = wq * 16 + q * 4 + r;
    float m0_ = Msm[0][row], m1_ = Msm[1][row], m2_ = Msm[2][row], m3_ = Msm[3][row];
    float mf_ = fmaxf(fmaxf(m0_, m1_), fmaxf(m2_, m3_));
    alr[r] = __expf(mrow[r] - mf_);
    if (wset == 0 && ln == 0) {
      float lf = __expf(m0_ - mf_) * Lsm[0][row] + __expf(m1_ - mf_) * Lsm[1][row]
               + __expf(m2_ - mf_) * Lsm[2][row] + __expf(m3_ - mf_) * Lsm[3][row];
      Ism[row] = 1.0f / lf;
    }
  }
  f32x4 alv = {alr[0], alr[1], alr[2], alr[3]};
#pragma unroll
  for (int cf = 0; cf < 16; ++cf) O[cf] *= alv;

  float* Obuf = (float*)TileMem;              // [64][260] fp32, overlays tiles
  __syncthreads();                            // all sets done reading Kt/Vt
  if (wset == 0) {
#pragma unroll
    for (int cf = 0; cf < 16; ++cf)
#pragma unroll
      for (int r = 0; r < 4; ++r)
        Obuf[(wq * 16 + q * 4 + r) * 260 + cf * 16 + ln] = O[cf][r];
  }
  __syncthreads();
  if (wset == 1) {
#pragma unroll
    for (int cf = 0; cf < 16; ++cf)
#pragma unroll
      for (int r = 0; r < 4; ++r)
        Obuf[(wq * 16 + q * 4 + r) * 260 + cf * 16 + ln] += O[cf][r];
  }
  __syncthreads();
  if (wset == 2) {
#pragma unroll
    for (int cf = 0; cf < 16; ++cf)
#pragma unroll
      for (int r = 0; r < 4; ++r)
        Obuf[(wq * 16 + q * 4 + r) * 260 + cf * 16 + ln] += O[cf][r];
  }
  __syncthreads();
  if (wset == 3) {
#pragma unroll
    for (int cf = 0; cf < 16; ++cf)
#pragma unroll
      for (int r = 0; r < 4; ++r)
        Obuf[(wq * 16 + q * 4 + r) * 260 + cf * 16 + ln] += O[cf][r];
  }
  __syncthreads();

  // final normalize + store: wave handles rows [wave*4, wave*4+4)
#pragma unroll
  for (int rr = 0; rr < 4; ++rr) {
    int row = wave * 4 + rr;
    float inv = Ism[row];
    f32x4 v = *(const f32x4*)(Obuf + row * 260 + lane * 4);
    us4 pk;
    pk.x = f2bf(v[0] * inv);
    pk.y = f2bf(v[1] * inv);
    pk.z = f2bf(v[2] * inv);
    pk.w = f2bf(v[3] * inv);
    *(us4*)(ctx + ((size_t)b * NSP + n0 + row) * CI + lane * 4) = pk;
  }
}

// ------------------------------------------------------ output conv
__global__ __launch_bounds__(256) void k_convout(
    const unsigned short* __restrict__ wo,    // [1024][256]
    const unsigned short* __restrict__ ctx,   // [B][4096][256]
    const float* __restrict__ bout,
    float* __restrict__ out)                  // [B][1024][4096]
{
  __shared__ __align__(16) unsigned short ldsA[128 * 64];
  __shared__ __align__(16) unsigned short ldsB[128 * 64];
  int b = blockIdx.z, m0 = blockIdx.y * 128, n0 = blockIdx.x * 128;
  int tid = threadIdx.x;
  f32x4 z = {0.f, 0.f, 0.f, 0.f};
  f32x4 acc[4][4];
#pragma unroll
  for (int i = 0; i < 4; ++i)
#pragma unroll
    for (int j = 0; j < 4; ++j) acc[i][j] = z;

  gemm_core<CI>(wo + (size_t)m0 * CI, ctx + ((size_t)b * NSP + n0) * CI,
                ldsA, ldsB, acc, tid);

  int lane = tid & 63, wave = tid >> 6, q = lane >> 4, ln = lane & 15;
  int wm = wave & 1, wn = wave >> 1;
#pragma unroll
  for (int mf = 0; mf < 4; ++mf) {
    int cb = m0 + wm * 64 + mf * 16 + q * 4;
    float bo0 = bout[cb + 0], bo1 = bout[cb + 1], bo2 = bout[cb + 2], bo3 = bout[cb + 3];
#pragma unroll
    for (int nf = 0; nf < 4; ++nf) {
      int n = n0 + wn * 64 + nf * 16 + ln;
      float* p = out + ((size_t)b * CO + cb) * NSP + n;
      p[0 * (size_t)NSP] = acc[mf][nf][0] + bo0;
      p[1 * (size_t)NSP] = acc[mf][nf][1] + bo1;
      p[2 * (size_t)NSP] = acc[mf][nf][2] + bo2;
      p[3 * (size_t)NSP] = acc[mf][nf][3] + bo3;
    }
  }
}

// ---------------------------------------------------------------- launch
extern "C" void kernel_launch(void* const* d_in, const int* in_sizes, int n_in,
                              void* d_out, int out_size, void* d_ws, size_t ws_size,
                              hipStream_t stream) {
  const float* x     = (const float*)d_in[0];
  const float* w_key = (const float*)d_in[1];
  const float* b_key = (const float*)d_in[2];
  const float* gamma = (const float*)d_in[3];
  const float* beta  = (const float*)d_in[4];
  const float* mean  = (const float*)d_in[5];
  const float* var   = (const float*)d_in[6];
  const float* w_val = (const float*)d_in[7];
  const float* b_val = (const float*)d_in[8];
  const float* w_out = (const float*)d_in[9];
  const float* b_out = (const float*)d_in[10];
  float* out = (float*)d_out;

  char* ws = (char*)d_ws;
  unsigned short* xT  = (unsigned short*)(ws);               // 32 MiB
  unsigned short* wkv = (unsigned short*)(ws + 33554432);    // 1 MiB
  unsigned short* wob = (unsigned short*)(ws + 34603008);    // 512 KiB
  unsigned short* qkT = (unsigned short*)(ws + 35127296);    // 8 MiB
  unsigned short* vv  = (unsigned short*)(ws + 43515904);    // 8 MiB
  unsigned short* ctx = (unsigned short*)(ws + 51904512);    // 8 MiB
  float* sq = (float*)(ws + 60293120);                       // 1 KiB
  float* bq = (float*)(ws + 60294144);                       // 1 KiB

  k_prep<<<2048, 256, 0, stream>>>(w_key, w_val, w_out, gamma, beta, mean, var,
                                   b_key, wkv, wob, sq, bq);
  k_xpose<<<dim3(64, 16, 4), 256, 0, stream>>>(x, xT);
  k_convqkv<<<dim3(32, 4, 4), 256, 0, stream>>>(wkv, xT, sq, bq, b_val, qkT, vv);
  k_attn<<<256, 1024, 0, stream>>>(qkT, vv, ctx);
  k_convout<<<dim3(32, 8, 4), 256, 0, stream>>>(wob, ctx, b_out, out);
}

// Round 4
// 362.418 us; speedup vs baseline: 1.6201x; 1.6040x over previous
//
#include <hip/hip_runtime.h>

#define BATCH 4
#define CIN   1024
#define CI    256
#define CO    1024
#define NSP   4096

typedef __attribute__((ext_vector_type(8))) short bf16x8;
typedef __attribute__((ext_vector_type(4))) float f32x4;

struct __align__(8) us4 { unsigned short x, y, z, w; };

#define DEVI __device__ __forceinline__

DEVI unsigned short f2bf(float f) {
  union { float f; unsigned u; } un; un.f = f;
  unsigned u = un.u;
  u += 0x7FFFu + ((u >> 16) & 1u);   // RNE
  return (unsigned short)(u >> 16);
}

DEVI void gl2lds16(const void* g, void* l) {
  __builtin_amdgcn_global_load_lds(
      (const __attribute__((address_space(1))) void*)g,
      (__attribute__((address_space(3))) void*)l, 16, 0, 0);
}

DEVI f32x4 mfma16(bf16x8 a, bf16x8 b, f32x4 c) {
  return __builtin_amdgcn_mfma_f32_16x16x32_bf16(a, b, c, 0, 0, 0);
}

// ---------------------------------------------------------------- prep small
__global__ __launch_bounds__(256) void k_prep(
    const float* __restrict__ w_key, const float* __restrict__ w_val,
    const float* __restrict__ w_out,
    const float* __restrict__ gamma, const float* __restrict__ beta,
    const float* __restrict__ mean,  const float* __restrict__ var,
    const float* __restrict__ b_key,
    unsigned short* __restrict__ wkv, unsigned short* __restrict__ wob,
    float* __restrict__ sq, float* __restrict__ bq)
{
  int idx = blockIdx.x * 256 + threadIdx.x;          // 0 .. 524287
  float wv = (idx < 262144) ? w_key[idx] : w_val[idx - 262144];
  wkv[idx] = f2bf(wv);
  if (idx < 262144) wob[idx] = f2bf(w_out[idx]);
  if (idx < 256) {
    float inv = gamma[idx] * rsqrtf(var[idx] + 1e-5f);
    sq[idx] = 0.25f * inv;                            // sqrt(1/16) folded into qk
    bq[idx] = 0.25f * (beta[idx] + (b_key[idx] - mean[idx]) * inv);
  }
}

// ------------------------------------------------------- x transpose -> bf16
__global__ __launch_bounds__(256) void k_xpose(const float* __restrict__ x,
                                               unsigned short* __restrict__ xT)
{
  __shared__ unsigned short tile[64][65];
  int b = blockIdx.z, k0 = blockIdx.y * 64, n0 = blockIdx.x * 64;
  int tid = threadIdx.x;
  int rr = tid >> 4, cc = tid & 15;
  const float* xb = x + ((size_t)b * CIN + k0) * NSP + n0;
#pragma unroll
  for (int p = 0; p < 4; ++p) {
    int row = p * 16 + rr;
    float4 v = *(const float4*)(xb + (size_t)row * NSP + cc * 4);
    tile[row][cc * 4 + 0] = f2bf(v.x);
    tile[row][cc * 4 + 1] = f2bf(v.y);
    tile[row][cc * 4 + 2] = f2bf(v.z);
    tile[row][cc * 4 + 3] = f2bf(v.w);
  }
  __syncthreads();
  unsigned short* xtb = xT + ((size_t)b * NSP + n0) * CIN + k0;
#pragma unroll
  for (int p = 0; p < 4; ++p) {
    int n = p * 16 + rr;
    int kq = cc * 4;
    us4 pk;
    pk.x = tile[kq + 0][n]; pk.y = tile[kq + 1][n];
    pk.z = tile[kq + 2][n]; pk.w = tile[kq + 3][n];
    *(us4*)(xtb + (size_t)n * CIN + kq) = pk;
  }
}

// -------------------------------------------- 128x128 NT GEMM core (bf16)
template<int KDIM>
DEVI void gemm_core(const unsigned short* __restrict__ Ab,
                    const unsigned short* __restrict__ Bb,
                    unsigned short* ldsA, unsigned short* ldsB,
                    f32x4 acc[4][4], int tid)
{
  const int lane = tid & 63, wave = tid >> 6;
  const int q = lane >> 4, ln = lane & 15;
  const int wm = wave & 1, wn = wave >> 1;

  int aoff[4][2], boff[4][2];
#pragma unroll
  for (int f = 0; f < 4; ++f) {
    int ra = wm * 64 + f * 16 + ln;
    aoff[f][0] = (ra * 8 + ((q)     ^ (ra & 7))) * 8;
    aoff[f][1] = (ra * 8 + ((q + 4) ^ (ra & 7))) * 8;
    int rb = wn * 64 + f * 16 + ln;
    boff[f][0] = (rb * 8 + ((q)     ^ (rb & 7))) * 8;
    boff[f][1] = (rb * 8 + ((q + 4) ^ (rb & 7))) * 8;
  }
  int sgo[4];
#pragma unroll
  for (int i = 0; i < 4; ++i) {
    int s = i * 256 + tid;
    int row = s >> 3;
    int c8 = (s & 7) ^ (row & 7);
    sgo[i] = row * KDIM + c8 * 8;
  }
  for (int k0 = 0; k0 < KDIM; k0 += 64) {
#pragma unroll
    for (int i = 0; i < 4; ++i) {
      gl2lds16(Ab + sgo[i] + k0, ldsA + (i * 256 + wave * 64) * 8);
      gl2lds16(Bb + sgo[i] + k0, ldsB + (i * 256 + wave * 64) * 8);
    }
    __syncthreads();
#pragma unroll
    for (int kk = 0; kk < 2; ++kk) {
      bf16x8 af[4], bfr[4];
#pragma unroll
      for (int f = 0; f < 4; ++f) af[f]  = *(const bf16x8*)(ldsA + aoff[f][kk]);
#pragma unroll
      for (int f = 0; f < 4; ++f) bfr[f] = *(const bf16x8*)(ldsB + boff[f][kk]);
#pragma unroll
      for (int mf = 0; mf < 4; ++mf)
#pragma unroll
        for (int nf = 0; nf < 4; ++nf)
          acc[mf][nf] = mfma16(af[mf], bfr[nf], acc[mf][nf]);
    }
    __syncthreads();
  }
}

// ------------------------------------------------- qk/value conv (fused)
__global__ __launch_bounds__(256) void k_convqkv(
    const unsigned short* __restrict__ wkv,   // [512][1024]
    const unsigned short* __restrict__ xT,    // [B][4096][1024]
    const float* __restrict__ sq, const float* __restrict__ bq,
    const float* __restrict__ bval,
    unsigned short* __restrict__ qkT,         // [B][4096][256]
    unsigned short* __restrict__ vv)          // [B][256][4096]
{
  __shared__ __align__(16) unsigned short ldsA[128 * 64];
  __shared__ __align__(16) unsigned short ldsB[128 * 64];
  int b = blockIdx.z, m0 = blockIdx.y * 128, n0 = blockIdx.x * 128;
  int tid = threadIdx.x;
  f32x4 z = {0.f, 0.f, 0.f, 0.f};
  f32x4 acc[4][4];
#pragma unroll
  for (int i = 0; i < 4; ++i)
#pragma unroll
    for (int j = 0; j < 4; ++j) acc[i][j] = z;

  gemm_core<CIN>(wkv + (size_t)m0 * CIN, xT + ((size_t)b * NSP + n0) * CIN,
                 ldsA, ldsB, acc, tid);

  int lane = tid & 63, wave = tid >> 6, q = lane >> 4, ln = lane & 15;
  int wm = wave & 1, wn = wave >> 1;
  if (m0 < 256) {
#pragma unroll
    for (int mf = 0; mf < 4; ++mf) {
      int cb = m0 + wm * 64 + mf * 16 + q * 4;
      float s0_ = sq[cb + 0], s1_ = sq[cb + 1], s2_ = sq[cb + 2], s3_ = sq[cb + 3];
      float b0_ = bq[cb + 0], b1_ = bq[cb + 1], b2_ = bq[cb + 2], b3_ = bq[cb + 3];
#pragma unroll
      for (int nf = 0; nf < 4; ++nf) {
        int n = n0 + wn * 64 + nf * 16 + ln;
        us4 pk;
        pk.x = f2bf(acc[mf][nf][0] * s0_ + b0_);
        pk.y = f2bf(acc[mf][nf][1] * s1_ + b1_);
        pk.z = f2bf(acc[mf][nf][2] * s2_ + b2_);
        pk.w = f2bf(acc[mf][nf][3] * s3_ + b3_);
        *(us4*)(qkT + ((size_t)b * NSP + n) * CI + cb) = pk;
      }
    }
  } else {
#pragma unroll
    for (int mf = 0; mf < 4; ++mf) {
      int cb = (m0 - 256) + wm * 64 + mf * 16 + q * 4;
#pragma unroll
      for (int r = 0; r < 4; ++r) {
        float bv = bval[cb + r];
#pragma unroll
        for (int nf = 0; nf < 4; ++nf) {
          int n = n0 + wn * 64 + nf * 16 + ln;
          vv[((size_t)b * CI + (cb + r)) * NSP + n] = f2bf(acc[mf][nf][r] + bv);
        }
      }
    }
  }
}

// ------------------------------------------------- fused attention, partial
// R0's proven 256-thread block (VGPR 124, no spill). 4-way j-split is ACROSS
// BLOCKS (1024 blocks = 4 blocks/CU, 16 waves/CU): block (qt,b,js) processes
// j in [js*1024, js*1024+1024) and writes fp32 partial O + per-row m,l.
// slice = bid & 15 so blocks sharing a (b,js) K/V slice land on one XCD's L2.
// R1-R3 lesson: 1024-thread blocks made the allocator pick 64 VGPR and spill
// O[16] to scratch (750 MB FETCH). Do not re-merge into one big block.
__global__ __launch_bounds__(256, 2) void k_attn_part(
    const unsigned short* __restrict__ qkT,   // [B][4096][256]
    const unsigned short* __restrict__ vv,    // [B][256][4096]
    float* __restrict__ Opart,                // [1024][64][256]
    float* __restrict__ Mpart,                // [1024][64]
    float* __restrict__ Lpart)                // [1024][64]
{
  __shared__ __align__(16) unsigned short Kt[32 * 256];  // [32 j][32 cc] swizzled
  __shared__ __align__(16) unsigned short Vt[256 * 32];  // [256 c][4 cc] swizzled
  __shared__ __align__(16) unsigned short Pl[4 * 512];   // per-wave [16 m][4 cc]

  int bid = blockIdx.x;                       // 1024 blocks
  int slice = bid & 15, qt = bid >> 4;
  int b = slice >> 2, js = slice & 3;
  int n0 = qt * 64;
  int tid = threadIdx.x, lane = tid & 63, wave = tid >> 6;
  int q = lane >> 4, ln = lane & 15;
  const unsigned short* qkb = qkT + (size_t)b * NSP * CI;
  const unsigned short* vb  = vv  + (size_t)b * CI * NSP;

  // Q fragments in registers: wave's 16 q-rows, all 256 channels
  bf16x8 Qf[8];
  {
    const unsigned short* qrow = qkb + (size_t)(n0 + wave * 16 + ln) * CI + q * 8;
#pragma unroll
    for (int t = 0; t < 8; ++t) Qf[t] = *(const bf16x8*)(qrow + t * 32);
  }

  int koff[2][8];
#pragma unroll
  for (int jj = 0; jj < 2; ++jj) {
    int j = jj * 16 + ln;
#pragma unroll
    for (int t = 0; t < 8; ++t) {
      int cc = t * 4 + q;
      koff[jj][t] = (j * 32 + ((cc & 24) | ((cc ^ j) & 7))) * 8;
    }
  }
  int voff[16];
#pragma unroll
  for (int cf = 0; cf < 16; ++cf) {
    int c = cf * 16 + ln;
    voff[cf] = (c * 4 + ((q ^ (c >> 1)) & 3)) * 8;
  }
  int proff = wave * 512 + (ln * 4 + ((q ^ (ln >> 1)) & 3)) * 8;
  int pw[2][4];
#pragma unroll
  for (int jj = 0; jj < 2; ++jj)
#pragma unroll
    for (int r = 0; r < 4; ++r) {
      int m = q * 4 + r;
      int j = jj * 16 + ln;
      int cc = j >> 3;
      pw[jj][r] = wave * 512 + (m * 4 + ((cc ^ (m >> 1)) & 3)) * 8 + (j & 7);
    }

  int gko[4], gvo[4];
#pragma unroll
  for (int i = 0; i < 4; ++i) {
    int s = i * 256 + tid;
    int j = s >> 5, f = s & 31;
    gko[i] = j * CI + ((f & 24) | ((f ^ j) & 7)) * 8;
    int c = s >> 2;
    gvo[i] = c * NSP + ((s ^ (c >> 1)) & 3) * 8;
  }

  f32x4 O[16];
  f32x4 z = {0.f, 0.f, 0.f, 0.f};
#pragma unroll
  for (int cf = 0; cf < 16; ++cf) O[cf] = z;
  float mrow[4] = {-1e30f, -1e30f, -1e30f, -1e30f};
  float lrow[4] = {0.f, 0.f, 0.f, 0.f};

  int jbase = js * 1024;
  for (int it = 0; it < 32; ++it) {
    int j0 = jbase + it * 32;
#pragma unroll
    for (int i = 0; i < 4; ++i)
      gl2lds16(qkb + (size_t)j0 * CI + gko[i], Kt + (i * 256 + wave * 64) * 8);
#pragma unroll
    for (int i = 0; i < 4; ++i)
      gl2lds16(vb + j0 + gvo[i], Vt + (i * 256 + wave * 64) * 8);
    __syncthreads();

    f32x4 s0 = z, s1 = z;
#pragma unroll
    for (int t = 0; t < 8; ++t) {
      bf16x8 kf0 = *(const bf16x8*)(Kt + koff[0][t]);
      bf16x8 kf1 = *(const bf16x8*)(Kt + koff[1][t]);
      s0 = mfma16(Qf[t], kf0, s0);
      s1 = mfma16(Qf[t], kf1, s1);
    }

    float alr[4];
#pragma unroll
    for (int r = 0; r < 4; ++r) {
      float v0 = s0[r], v1 = s1[r];
      float mx = fmaxf(v0, v1);
      mx = fmaxf(mx, __shfl_xor(mx, 1));
      mx = fmaxf(mx, __shfl_xor(mx, 2));
      mx = fmaxf(mx, __shfl_xor(mx, 4));
      mx = fmaxf(mx, __shfl_xor(mx, 8));
      float mnew = fmaxf(mrow[r], mx);
      float p0 = __expf(v0 - mnew);
      float p1 = __expf(v1 - mnew);
      float al = __expf(mrow[r] - mnew);
      float sm = p0 + p1;
      sm += __shfl_xor(sm, 1);
      sm += __shfl_xor(sm, 2);
      sm += __shfl_xor(sm, 4);
      sm += __shfl_xor(sm, 8);
      lrow[r] = lrow[r] * al + sm;
      mrow[r] = mnew;
      alr[r] = al;
      Pl[pw[0][r]] = f2bf(p0);
      Pl[pw[1][r]] = f2bf(p1);
    }
    f32x4 alv = {alr[0], alr[1], alr[2], alr[3]};
#pragma unroll
    for (int cf = 0; cf < 16; ++cf) O[cf] *= alv;

    bf16x8 pf = *(const bf16x8*)(Pl + proff);
#pragma unroll
    for (int cf = 0; cf < 16; ++cf) {
      bf16x8 vf = *(const bf16x8*)(Vt + voff[cf]);
      O[cf] = mfma16(pf, vf, O[cf]);
    }
    __syncthreads();
  }

  // write fp32 partials (unnormalized) + m,l
  float* Ob = Opart + (size_t)bid * (64 * 256);
#pragma unroll
  for (int r = 0; r < 4; ++r) {
    int row = wave * 16 + q * 4 + r;
    if (ln == 0) {
      Mpart[bid * 64 + row] = mrow[r];
      Lpart[bid * 64 + row] = lrow[r];
    }
#pragma unroll
    for (int cf = 0; cf < 16; ++cf)
      Ob[row * 256 + cf * 16 + ln] = O[cf][r];
  }
}

// ------------------------------------------------- split-k softmax merge
__global__ __launch_bounds__(256) void k_merge(
    const float* __restrict__ Opart,          // [1024][64][256]
    const float* __restrict__ Mpart,          // [1024][64]
    const float* __restrict__ Lpart,          // [1024][64]
    unsigned short* __restrict__ ctx)         // [B][4096][256]
{
  __shared__ float Wm[4][64];
  int mb = blockIdx.x;                        // 256: one per (b,qt)
  int b = mb >> 6, qt = mb & 63;
  int tid = threadIdx.x;
  int pb0 = qt * 16 + b * 4;                  // partial block base (js=0..3)

  if (tid < 64) {
    float m0 = Mpart[(pb0 + 0) * 64 + tid];
    float m1 = Mpart[(pb0 + 1) * 64 + tid];
    float m2 = Mpart[(pb0 + 2) * 64 + tid];
    float m3 = Mpart[(pb0 + 3) * 64 + tid];
    float M = fmaxf(fmaxf(m0, m1), fmaxf(m2, m3));
    float e0 = __expf(m0 - M), e1 = __expf(m1 - M);
    float e2 = __expf(m2 - M), e3 = __expf(m3 - M);
    float L = e0 * Lpart[(pb0 + 0) * 64 + tid] + e1 * Lpart[(pb0 + 1) * 64 + tid]
            + e2 * Lpart[(pb0 + 2) * 64 + tid] + e3 * Lpart[(pb0 + 3) * 64 + tid];
    float inv = 1.0f / L;
    Wm[0][tid] = e0 * inv; Wm[1][tid] = e1 * inv;
    Wm[2][tid] = e2 * inv; Wm[3][tid] = e3 * inv;
  }
  __syncthreads();

  const float* O0 = Opart + (size_t)(pb0 + 0) * (64 * 256);
  const float* O1 = Opart + (size_t)(pb0 + 1) * (64 * 256);
  const float* O2 = Opart + (size_t)(pb0 + 2) * (64 * 256);
  const float* O3 = Opart + (size_t)(pb0 + 3) * (64 * 256);
  unsigned short* cb = ctx + ((size_t)b * NSP + qt * 64) * CI;
#pragma unroll 4
  for (int row = 0; row < 64; ++row) {
    float a = Wm[0][row] * O0[row * 256 + tid] + Wm[1][row] * O1[row * 256 + tid]
            + Wm[2][row] * O2[row * 256 + tid] + Wm[3][row] * O3[row * 256 + tid];
    cb[(size_t)row * CI + tid] = f2bf(a);
  }
}

// ------------------------------------------------------ output conv
__global__ __launch_bounds__(256) void k_convout(
    const unsigned short* __restrict__ wo,    // [1024][256]
    const unsigned short* __restrict__ ctx,   // [B][4096][256]
    const float* __restrict__ bout,
    float* __restrict__ out)                  // [B][1024][4096]
{
  __shared__ __align__(16) unsigned short ldsA[128 * 64];
  __shared__ __align__(16) unsigned short ldsB[128 * 64];
  int b = blockIdx.z, m0 = blockIdx.y * 128, n0 = blockIdx.x * 128;
  int tid = threadIdx.x;
  f32x4 z = {0.f, 0.f, 0.f, 0.f};
  f32x4 acc[4][4];
#pragma unroll
  for (int i = 0; i < 4; ++i)
#pragma unroll
    for (int j = 0; j < 4; ++j) acc[i][j] = z;

  gemm_core<CI>(wo + (size_t)m0 * CI, ctx + ((size_t)b * NSP + n0) * CI,
                ldsA, ldsB, acc, tid);

  int lane = tid & 63, wave = tid >> 6, q = lane >> 4, ln = lane & 15;
  int wm = wave & 1, wn = wave >> 1;
#pragma unroll
  for (int mf = 0; mf < 4; ++mf) {
    int cb = m0 + wm * 64 + mf * 16 + q * 4;
    float bo0 = bout[cb + 0], bo1 = bout[cb + 1], bo2 = bout[cb + 2], bo3 = bout[cb + 3];
#pragma unroll
    for (int nf = 0; nf < 4; ++nf) {
      int n = n0 + wn * 64 + nf * 16 + ln;
      float* p = out + ((size_t)b * CO + cb) * NSP + n;
      p[0 * (size_t)NSP] = acc[mf][nf][0] + bo0;
      p[1 * (size_t)NSP] = acc[mf][nf][1] + bo1;
      p[2 * (size_t)NSP] = acc[mf][nf][2] + bo2;
      p[3 * (size_t)NSP] = acc[mf][nf][3] + bo3;
    }
  }
}

// ---------------------------------------------------------------- launch
extern "C" void kernel_launch(void* const* d_in, const int* in_sizes, int n_in,
                              void* d_out, int out_size, void* d_ws, size_t ws_size,
                              hipStream_t stream) {
  const float* x     = (const float*)d_in[0];
  const float* w_key = (const float*)d_in[1];
  const float* b_key = (const float*)d_in[2];
  const float* gamma = (const float*)d_in[3];
  const float* beta  = (const float*)d_in[4];
  const float* mean  = (const float*)d_in[5];
  const float* var   = (const float*)d_in[6];
  const float* w_val = (const float*)d_in[7];
  const float* b_val = (const float*)d_in[8];
  const float* w_out = (const float*)d_in[9];
  const float* b_out = (const float*)d_in[10];
  float* out = (float*)d_out;

  char* ws = (char*)d_ws;
  unsigned short* xT  = (unsigned short*)(ws);               // 32 MiB
  unsigned short* wkv = (unsigned short*)(ws + 33554432);    // 1 MiB
  unsigned short* wob = (unsigned short*)(ws + 34603008);    // 512 KiB
  unsigned short* qkT = (unsigned short*)(ws + 35127296);    // 8 MiB
  unsigned short* vv  = (unsigned short*)(ws + 43515904);    // 8 MiB
  unsigned short* ctx = (unsigned short*)(ws + 51904512);    // 8 MiB
  float* sq = (float*)(ws + 60293120);                       // 1 KiB
  float* bq = (float*)(ws + 60294144);                       // 1 KiB
  float* Opart = (float*)(ws + 60295168);                    // 64 MiB
  float* Mpart = (float*)(ws + 127404032);                   // 256 KiB
  float* Lpart = (float*)(ws + 127666176);                   // 256 KiB

  k_prep<<<2048, 256, 0, stream>>>(w_key, w_val, w_out, gamma, beta, mean, var,
                                   b_key, wkv, wob, sq, bq);
  k_xpose<<<dim3(64, 16, 4), 256, 0, stream>>>(x, xT);
  k_convqkv<<<dim3(32, 4, 4), 256, 0, stream>>>(wkv, xT, sq, bq, b_val, qkT, vv);
  k_attn_part<<<1024, 256, 0, stream>>>(qkT, vv, Opart, Mpart, Lpart);
  k_merge<<<256, 256, 0, stream>>>(Opart, Mpart, Lpart, ctx);
  k_convout<<<dim3(32, 8, 4), 256, 0, stream>>>(wob, ctx, b_out, out);
}

// Round 5
// 348.734 us; speedup vs baseline: 1.6836x; 1.0392x over previous
//
#include <hip/hip_runtime.h>

#define BATCH 4
#define CIN   1024
#define CI    256
#define CO    1024
#define NSP   4096

typedef __attribute__((ext_vector_type(8))) short bf16x8;
typedef __attribute__((ext_vector_type(4))) float f32x4;

struct __align__(8) us4 { unsigned short x, y, z, w; };

#define DEVI __device__ __forceinline__

DEVI unsigned short f2bf(float f) {
  union { float f; unsigned u; } un; un.f = f;
  unsigned u = un.u;
  u += 0x7FFFu + ((u >> 16) & 1u);   // RNE
  return (unsigned short)(u >> 16);
}

DEVI void gl2lds16(const void* g, void* l) {
  __builtin_amdgcn_global_load_lds(
      (const __attribute__((address_space(1))) void*)g,
      (__attribute__((address_space(3))) void*)l, 16, 0, 0);
}

DEVI f32x4 mfma16(bf16x8 a, bf16x8 b, f32x4 c) {
  return __builtin_amdgcn_mfma_f32_16x16x32_bf16(a, b, c, 0, 0, 0);
}

// ---------------------------------------------------------------- prep small
__global__ __launch_bounds__(256) void k_prep(
    const float* __restrict__ w_key, const float* __restrict__ w_val,
    const float* __restrict__ w_out,
    const float* __restrict__ gamma, const float* __restrict__ beta,
    const float* __restrict__ mean,  const float* __restrict__ var,
    const float* __restrict__ b_key,
    unsigned short* __restrict__ wkv, unsigned short* __restrict__ wob,
    float* __restrict__ sq, float* __restrict__ bq)
{
  int idx = blockIdx.x * 256 + threadIdx.x;          // 0 .. 524287
  float wv = (idx < 262144) ? w_key[idx] : w_val[idx - 262144];
  wkv[idx] = f2bf(wv);
  if (idx < 262144) wob[idx] = f2bf(w_out[idx]);
  if (idx < 256) {
    float inv = gamma[idx] * rsqrtf(var[idx] + 1e-5f);
    sq[idx] = 0.25f * inv;                            // sqrt(1/16) folded into qk
    bq[idx] = 0.25f * (beta[idx] + (b_key[idx] - mean[idx]) * inv);
  }
}

// ------------------------------------------------------- x transpose -> bf16
__global__ __launch_bounds__(256) void k_xpose(const float* __restrict__ x,
                                               unsigned short* __restrict__ xT)
{
  __shared__ unsigned short tile[64][65];
  int b = blockIdx.z, k0 = blockIdx.y * 64, n0 = blockIdx.x * 64;
  int tid = threadIdx.x;
  int rr = tid >> 4, cc = tid & 15;
  const float* xb = x + ((size_t)b * CIN + k0) * NSP + n0;
#pragma unroll
  for (int p = 0; p < 4; ++p) {
    int row = p * 16 + rr;
    float4 v = *(const float4*)(xb + (size_t)row * NSP + cc * 4);
    tile[row][cc * 4 + 0] = f2bf(v.x);
    tile[row][cc * 4 + 1] = f2bf(v.y);
    tile[row][cc * 4 + 2] = f2bf(v.z);
    tile[row][cc * 4 + 3] = f2bf(v.w);
  }
  __syncthreads();
  unsigned short* xtb = xT + ((size_t)b * NSP + n0) * CIN + k0;
#pragma unroll
  for (int p = 0; p < 4; ++p) {
    int n = p * 16 + rr;
    int kq = cc * 4;
    us4 pk;
    pk.x = tile[kq + 0][n]; pk.y = tile[kq + 1][n];
    pk.z = tile[kq + 2][n]; pk.w = tile[kq + 3][n];
    *(us4*)(xtb + (size_t)n * CIN + kq) = pk;
  }
}

// -------------------------------------------- 128x128 NT GEMM core (bf16)
template<int KDIM>
DEVI void gemm_core(const unsigned short* __restrict__ Ab,
                    const unsigned short* __restrict__ Bb,
                    unsigned short* ldsA, unsigned short* ldsB,
                    f32x4 acc[4][4], int tid)
{
  const int lane = tid & 63, wave = tid >> 6;
  const int q = lane >> 4, ln = lane & 15;
  const int wm = wave & 1, wn = wave >> 1;

  int aoff[4][2], boff[4][2];
#pragma unroll
  for (int f = 0; f < 4; ++f) {
    int ra = wm * 64 + f * 16 + ln;
    aoff[f][0] = (ra * 8 + ((q)     ^ (ra & 7))) * 8;
    aoff[f][1] = (ra * 8 + ((q + 4) ^ (ra & 7))) * 8;
    int rb = wn * 64 + f * 16 + ln;
    boff[f][0] = (rb * 8 + ((q)     ^ (rb & 7))) * 8;
    boff[f][1] = (rb * 8 + ((q + 4) ^ (rb & 7))) * 8;
  }
  int sgo[4];
#pragma unroll
  for (int i = 0; i < 4; ++i) {
    int s = i * 256 + tid;
    int row = s >> 3;
    int c8 = (s & 7) ^ (row & 7);
    sgo[i] = row * KDIM + c8 * 8;
  }
  for (int k0 = 0; k0 < KDIM; k0 += 64) {
#pragma unroll
    for (int i = 0; i < 4; ++i) {
      gl2lds16(Ab + sgo[i] + k0, ldsA + (i * 256 + wave * 64) * 8);
      gl2lds16(Bb + sgo[i] + k0, ldsB + (i * 256 + wave * 64) * 8);
    }
    __syncthreads();
#pragma unroll
    for (int kk = 0; kk < 2; ++kk) {
      bf16x8 af[4], bfr[4];
#pragma unroll
      for (int f = 0; f < 4; ++f) af[f]  = *(const bf16x8*)(ldsA + aoff[f][kk]);
#pragma unroll
      for (int f = 0; f < 4; ++f) bfr[f] = *(const bf16x8*)(ldsB + boff[f][kk]);
#pragma unroll
      for (int mf = 0; mf < 4; ++mf)
#pragma unroll
        for (int nf = 0; nf < 4; ++nf)
          acc[mf][nf] = mfma16(af[mf], bfr[nf], acc[mf][nf]);
    }
    __syncthreads();
  }
}

// ------------------------------------------------- qk/value conv (fused)
__global__ __launch_bounds__(256) void k_convqkv(
    const unsigned short* __restrict__ wkv,   // [512][1024]
    const unsigned short* __restrict__ xT,    // [B][4096][1024]
    const float* __restrict__ sq, const float* __restrict__ bq,
    const float* __restrict__ bval,
    unsigned short* __restrict__ qkT,         // [B][4096][256]
    unsigned short* __restrict__ vv)          // [B][256][4096]
{
  __shared__ __align__(16) unsigned short ldsA[128 * 64];
  __shared__ __align__(16) unsigned short ldsB[128 * 64];
  int b = blockIdx.z, m0 = blockIdx.y * 128, n0 = blockIdx.x * 128;
  int tid = threadIdx.x;
  f32x4 z = {0.f, 0.f, 0.f, 0.f};
  f32x4 acc[4][4];
#pragma unroll
  for (int i = 0; i < 4; ++i)
#pragma unroll
    for (int j = 0; j < 4; ++j) acc[i][j] = z;

  gemm_core<CIN>(wkv + (size_t)m0 * CIN, xT + ((size_t)b * NSP + n0) * CIN,
                 ldsA, ldsB, acc, tid);

  int lane = tid & 63, wave = tid >> 6, q = lane >> 4, ln = lane & 15;
  int wm = wave & 1, wn = wave >> 1;
  if (m0 < 256) {
#pragma unroll
    for (int mf = 0; mf < 4; ++mf) {
      int cb = m0 + wm * 64 + mf * 16 + q * 4;
      float s0_ = sq[cb + 0], s1_ = sq[cb + 1], s2_ = sq[cb + 2], s3_ = sq[cb + 3];
      float b0_ = bq[cb + 0], b1_ = bq[cb + 1], b2_ = bq[cb + 2], b3_ = bq[cb + 3];
#pragma unroll
      for (int nf = 0; nf < 4; ++nf) {
        int n = n0 + wn * 64 + nf * 16 + ln;
        us4 pk;
        pk.x = f2bf(acc[mf][nf][0] * s0_ + b0_);
        pk.y = f2bf(acc[mf][nf][1] * s1_ + b1_);
        pk.z = f2bf(acc[mf][nf][2] * s2_ + b2_);
        pk.w = f2bf(acc[mf][nf][3] * s3_ + b3_);
        *(us4*)(qkT + ((size_t)b * NSP + n) * CI + cb) = pk;
      }
    }
  } else {
#pragma unroll
    for (int mf = 0; mf < 4; ++mf) {
      int cb = (m0 - 256) + wm * 64 + mf * 16 + q * 4;
#pragma unroll
      for (int r = 0; r < 4; ++r) {
        float bv = bval[cb + r];
#pragma unroll
        for (int nf = 0; nf < 4; ++nf) {
          int n = n0 + wn * 64 + nf * 16 + ln;
          vv[((size_t)b * CI + (cb + r)) * NSP + n] = f2bf(acc[mf][nf][r] + bv);
        }
      }
    }
  }
}

// ------------------------------------------------- fused attention, partial
// 256-thread block (no spill), 1024 blocks, 4-way j-split across blocks.
// R5: S is computed TRANSPOSED (St[j][m] via mfma(A=K, B=Q) — A/B fragments
// have identical lane layouts, so LDS data is unchanged). j-reduction becomes
// 4 in-register values + 2 shfl_xor(16,32) for all 16 rows at once, instead
// of 4 rows x 8 shfl rounds. P written to LDS as 2 x b64 instead of 8 x b16.
__global__ __launch_bounds__(256, 2) void k_attn_part(
    const unsigned short* __restrict__ qkT,   // [B][4096][256]
    const unsigned short* __restrict__ vv,    // [B][256][4096]
    float* __restrict__ Opart,                // [1024][64][256]
    float* __restrict__ Mpart,                // [1024][64]
    float* __restrict__ Lpart)                // [1024][64]
{
  __shared__ __align__(16) unsigned short Kt[32 * 256];  // [32 j][32 cc] swizzled
  __shared__ __align__(16) unsigned short Vt[256 * 32];  // [256 c][4 cc] swizzled
  __shared__ __align__(16) unsigned short Pl[4 * 16 * 40]; // per-wave [16 m][40]

  int bid = blockIdx.x;                       // 1024 blocks
  int slice = bid & 15, qt = bid >> 4;
  int b = slice >> 2, js = slice & 3;
  int n0 = qt * 64;
  int tid = threadIdx.x, lane = tid & 63, wave = tid >> 6;
  int q = lane >> 4, ln = lane & 15;
  const unsigned short* qkb = qkT + (size_t)b * NSP * CI;
  const unsigned short* vb  = vv  + (size_t)b * CI * NSP;

  // Q fragments in registers: wave's 16 q-rows, all 256 channels
  bf16x8 Qf[8];
  {
    const unsigned short* qrow = qkb + (size_t)(n0 + wave * 16 + ln) * CI + q * 8;
#pragma unroll
    for (int t = 0; t < 8; ++t) Qf[t] = *(const bf16x8*)(qrow + t * 32);
  }

  int koff[2][8];
#pragma unroll
  for (int jj = 0; jj < 2; ++jj) {
    int j = jj * 16 + ln;
#pragma unroll
    for (int t = 0; t < 8; ++t) {
      int cc = t * 4 + q;
      koff[jj][t] = (j * 32 + ((cc & 24) | ((cc ^ j) & 7))) * 8;
    }
  }
  int voff[16];
#pragma unroll
  for (int cf = 0; cf < 16; ++cf) {
    int c = cf * 16 + ln;
    voff[cf] = (c * 4 + ((q ^ (c >> 1)) & 3)) * 8;
  }
  // P LDS: per-wave [16 m][40] (stride 40 shorts = 80 B keeps b64 writes and
  // b128 reads 16B-aligned and bank-spread). Write: lane (q,ln) packs 4
  // consecutive j = t*16 + q*4 + r for row m=ln. Read: row m=ln, j-chunk q*8.
  unsigned short* Plw = Pl + wave * (16 * 40);
  int pwo0 = ln * 40 + 0  + q * 4;            // tile0: j 0..15
  int pwo1 = ln * 40 + 16 + q * 4;            // tile1: j 16..31
  int pro  = ln * 40 + q * 8;                 // A-frag read

  int gko[4], gvo[4];
#pragma unroll
  for (int i = 0; i < 4; ++i) {
    int s = i * 256 + tid;
    int j = s >> 5, f = s & 31;
    gko[i] = j * CI + ((f & 24) | ((f ^ j) & 7)) * 8;
    int c = s >> 2;
    gvo[i] = c * NSP + ((s ^ (c >> 1)) & 3) * 8;
  }

  f32x4 O[16];
  f32x4 z = {0.f, 0.f, 0.f, 0.f};
#pragma unroll
  for (int cf = 0; cf < 16; ++cf) O[cf] = z;
  float mcur = -1e30f, lcur = 0.f;            // per-lane state for row m=ln

  int jbase = js * 1024;
  for (int it = 0; it < 32; ++it) {
    int j0 = jbase + it * 32;
#pragma unroll
    for (int i = 0; i < 4; ++i)
      gl2lds16(qkb + (size_t)j0 * CI + gko[i], Kt + (i * 256 + wave * 64) * 8);
#pragma unroll
    for (int i = 0; i < 4; ++i)
      gl2lds16(vb + j0 + gvo[i], Vt + (i * 256 + wave * 64) * 8);
    __syncthreads();

    // St[j][m]: col m = lane&15, row j = quad*4 + reg
    f32x4 s0 = z, s1 = z;
#pragma unroll
    for (int t = 0; t < 8; ++t) {
      bf16x8 kf0 = *(const bf16x8*)(Kt + koff[0][t]);
      bf16x8 kf1 = *(const bf16x8*)(Kt + koff[1][t]);
      s0 = mfma16(kf0, Qf[t], s0);
      s1 = mfma16(kf1, Qf[t], s1);
    }

    // online softmax, all 16 rows in parallel across lanes
    float smax = fmaxf(fmaxf(fmaxf(s0[0], s0[1]), fmaxf(s0[2], s0[3])),
                       fmaxf(fmaxf(s1[0], s1[1]), fmaxf(s1[2], s1[3])));
    smax = fmaxf(smax, __shfl_xor(smax, 16));
    smax = fmaxf(smax, __shfl_xor(smax, 32));
    float mnew = fmaxf(mcur, smax);
    float al = __expf(mcur - mnew);
    float p00 = __expf(s0[0] - mnew), p01 = __expf(s0[1] - mnew);
    float p02 = __expf(s0[2] - mnew), p03 = __expf(s0[3] - mnew);
    float p10 = __expf(s1[0] - mnew), p11 = __expf(s1[1] - mnew);
    float p12 = __expf(s1[2] - mnew), p13 = __expf(s1[3] - mnew);
    float psum = ((p00 + p01) + (p02 + p03)) + ((p10 + p11) + (p12 + p13));
    psum += __shfl_xor(psum, 16);
    psum += __shfl_xor(psum, 32);
    lcur = lcur * al + psum;
    mcur = mnew;

    us4 w0; w0.x = f2bf(p00); w0.y = f2bf(p01); w0.z = f2bf(p02); w0.w = f2bf(p03);
    us4 w1; w1.x = f2bf(p10); w1.y = f2bf(p11); w1.z = f2bf(p12); w1.w = f2bf(p13);
    *(us4*)(Plw + pwo0) = w0;
    *(us4*)(Plw + pwo1) = w1;

    // alpha for O rows (row m_o = q*4 + r lives in lane m_o's al)
    f32x4 alv;
    alv[0] = __shfl(al, q * 4 + 0);
    alv[1] = __shfl(al, q * 4 + 1);
    alv[2] = __shfl(al, q * 4 + 2);
    alv[3] = __shfl(al, q * 4 + 3);
#pragma unroll
    for (int cf = 0; cf < 16; ++cf) O[cf] *= alv;

    bf16x8 pf = *(const bf16x8*)(Plw + pro);
#pragma unroll
    for (int cf = 0; cf < 16; ++cf) {
      bf16x8 vf = *(const bf16x8*)(Vt + voff[cf]);
      O[cf] = mfma16(pf, vf, O[cf]);
    }
    __syncthreads();
  }

  // write fp32 partials (unnormalized) + m,l
  float* Ob = Opart + (size_t)bid * (64 * 256);
  if (lane < 16) {
    Mpart[bid * 64 + wave * 16 + lane] = mcur;
    Lpart[bid * 64 + wave * 16 + lane] = lcur;
  }
#pragma unroll
  for (int r = 0; r < 4; ++r) {
    int row = wave * 16 + q * 4 + r;
#pragma unroll
    for (int cf = 0; cf < 16; ++cf)
      Ob[row * 256 + cf * 16 + ln] = O[cf][r];
  }
}

// ------------------------------------------------- split-k softmax merge
__global__ __launch_bounds__(256) void k_merge(
    const float* __restrict__ Opart,          // [1024][64][256]
    const float* __restrict__ Mpart,          // [1024][64]
    const float* __restrict__ Lpart,          // [1024][64]
    unsigned short* __restrict__ ctx)         // [B][4096][256]
{
  __shared__ float Wm[4][64];
  int mb = blockIdx.x;                        // 256: one per (b,qt)
  int b = mb >> 6, qt = mb & 63;
  int tid = threadIdx.x;
  int pb0 = qt * 16 + b * 4;                  // partial block base (js=0..3)

  if (tid < 64) {
    float m0 = Mpart[(pb0 + 0) * 64 + tid];
    float m1 = Mpart[(pb0 + 1) * 64 + tid];
    float m2 = Mpart[(pb0 + 2) * 64 + tid];
    float m3 = Mpart[(pb0 + 3) * 64 + tid];
    float M = fmaxf(fmaxf(m0, m1), fmaxf(m2, m3));
    float e0 = __expf(m0 - M), e1 = __expf(m1 - M);
    float e2 = __expf(m2 - M), e3 = __expf(m3 - M);
    float L = e0 * Lpart[(pb0 + 0) * 64 + tid] + e1 * Lpart[(pb0 + 1) * 64 + tid]
            + e2 * Lpart[(pb0 + 2) * 64 + tid] + e3 * Lpart[(pb0 + 3) * 64 + tid];
    float inv = 1.0f / L;
    Wm[0][tid] = e0 * inv; Wm[1][tid] = e1 * inv;
    Wm[2][tid] = e2 * inv; Wm[3][tid] = e3 * inv;
  }
  __syncthreads();

  const float* O0 = Opart + (size_t)(pb0 + 0) * (64 * 256);
  const float* O1 = Opart + (size_t)(pb0 + 1) * (64 * 256);
  const float* O2 = Opart + (size_t)(pb0 + 2) * (64 * 256);
  const float* O3 = Opart + (size_t)(pb0 + 3) * (64 * 256);
  unsigned short* cb = ctx + ((size_t)b * NSP + qt * 64) * CI;
#pragma unroll 4
  for (int row = 0; row < 64; ++row) {
    float a = Wm[0][row] * O0[row * 256 + tid] + Wm[1][row] * O1[row * 256 + tid]
            + Wm[2][row] * O2[row * 256 + tid] + Wm[3][row] * O3[row * 256 + tid];
    cb[(size_t)row * CI + tid] = f2bf(a);
  }
}

// ------------------------------------------------------ output conv
__global__ __launch_bounds__(256) void k_convout(
    const unsigned short* __restrict__ wo,    // [1024][256]
    const unsigned short* __restrict__ ctx,   // [B][4096][256]
    const float* __restrict__ bout,
    float* __restrict__ out)                  // [B][1024][4096]
{
  __shared__ __align__(16) unsigned short ldsA[128 * 64];
  __shared__ __align__(16) unsigned short ldsB[128 * 64];
  int b = blockIdx.z, m0 = blockIdx.y * 128, n0 = blockIdx.x * 128;
  int tid = threadIdx.x;
  f32x4 z = {0.f, 0.f, 0.f, 0.f};
  f32x4 acc[4][4];
#pragma unroll
  for (int i = 0; i < 4; ++i)
#pragma unroll
    for (int j = 0; j < 4; ++j) acc[i][j] = z;

  gemm_core<CI>(wo + (size_t)m0 * CI, ctx + ((size_t)b * NSP + n0) * CI,
                ldsA, ldsB, acc, tid);

  int lane = tid & 63, wave = tid >> 6, q = lane >> 4, ln = lane & 15;
  int wm = wave & 1, wn = wave >> 1;
#pragma unroll
  for (int mf = 0; mf < 4; ++mf) {
    int cb = m0 + wm * 64 + mf * 16 + q * 4;
    float bo0 = bout[cb + 0], bo1 = bout[cb + 1], bo2 = bout[cb + 2], bo3 = bout[cb + 3];
#pragma unroll
    for (int nf = 0; nf < 4; ++nf) {
      int n = n0 + wn * 64 + nf * 16 + ln;
      float* p = out + ((size_t)b * CO + cb) * NSP + n;
      p[0 * (size_t)NSP] = acc[mf][nf][0] + bo0;
      p[1 * (size_t)NSP] = acc[mf][nf][1] + bo1;
      p[2 * (size_t)NSP] = acc[mf][nf][2] + bo2;
      p[3 * (size_t)NSP] = acc[mf][nf][3] + bo3;
    }
  }
}

// ---------------------------------------------------------------- launch
extern "C" void kernel_launch(void* const* d_in, const int* in_sizes, int n_in,
                              void* d_out, int out_size, void* d_ws, size_t ws_size,
                              hipStream_t stream) {
  const float* x     = (const float*)d_in[0];
  const float* w_key = (const float*)d_in[1];
  const float* b_key = (const float*)d_in[2];
  const float* gamma = (const float*)d_in[3];
  const float* beta  = (const float*)d_in[4];
  const float* mean  = (const float*)d_in[5];
  const float* var   = (const float*)d_in[6];
  const float* w_val = (const float*)d_in[7];
  const float* b_val = (const float*)d_in[8];
  const float* w_out = (const float*)d_in[9];
  const float* b_out = (const float*)d_in[10];
  float* out = (float*)d_out;

  char* ws = (char*)d_ws;
  unsigned short* xT  = (unsigned short*)(ws);               // 32 MiB
  unsigned short* wkv = (unsigned short*)(ws + 33554432);    // 1 MiB
  unsigned short* wob = (unsigned short*)(ws + 34603008);    // 512 KiB
  unsigned short* qkT = (unsigned short*)(ws + 35127296);    // 8 MiB
  unsigned short* vv  = (unsigned short*)(ws + 43515904);    // 8 MiB
  unsigned short* ctx = (unsigned short*)(ws + 51904512);    // 8 MiB
  float* sq = (float*)(ws + 60293120);                       // 1 KiB
  float* bq = (float*)(ws + 60294144);                       // 1 KiB
  float* Opart = (float*)(ws + 60295168);                    // 64 MiB
  float* Mpart = (float*)(ws + 127404032);                   // 256 KiB
  float* Lpart = (float*)(ws + 127666176);                   // 256 KiB

  k_prep<<<2048, 256, 0, stream>>>(w_key, w_val, w_out, gamma, beta, mean, var,
                                   b_key, wkv, wob, sq, bq);
  k_xpose<<<dim3(64, 16, 4), 256, 0, stream>>>(x, xT);
  k_convqkv<<<dim3(32, 4, 4), 256, 0, stream>>>(wkv, xT, sq, bq, b_val, qkT, vv);
  k_attn_part<<<1024, 256, 0, stream>>>(qkT, vv, Opart, Mpart, Lpart);
  k_merge<<<256, 256, 0, stream>>>(Opart, Mpart, Lpart, ctx);
  k_convout<<<dim3(32, 8, 4), 256, 0, stream>>>(wob, ctx, b_out, out);
}